// Round 11
// baseline (761.363 us; speedup 1.0000x reference)
//
#include <hip/hip_runtime.h>

// QRNN fused: causal conv1d(window=2) as f16 MFMA GEMM + gates + fo-pool scan.
// Shapes: B=8, T=2048, C=1024, U=1024 -> GEMM M=16384, K=2048, N=3072.
// R11: R9 single-barrier skeleton + WAVE ROLE-SPLIT: the two SIMD-sharing wave
//      groups (wm=0 vs wm=1) traverse quadrants in OPPOSITE order with reads
//      interleaved between MFMA clusters, so one group's ds_read burst lands in
//      the other group's MFMA window (R5-R10: lockstep waves => LDS+MFMA pipes
//      execute as a SUM, 42-48% plateau; B-reg bypass (R10) regressed badly).

typedef _Float16 f16;
typedef _Float16 f16x8 __attribute__((ext_vector_type(8)));
typedef float    f32x4 __attribute__((ext_vector_type(4)));

#define Bq 8
#define Tq 2048
#define Cq 1024
#define Uq 1024
#define Mq (Bq*Tq)    // 16384
#define Kq (2*Cq)     // 2048
#define Nq (3*Uq)     // 3072
#define NCH 32
#define CHL (Tq/NCH)

#define AS1 __attribute__((address_space(1)))
#define AS3 __attribute__((address_space(3)))

// ---------------- prep: Xs[b][1+t][c] = x[b][t][c] (f16), Xs[b][0][:] = 0 ----------------
__global__ void prep_xs(const float* __restrict__ x, f16* __restrict__ Xs) {
    long long idx = ((long long)blockIdx.x * blockDim.x + threadIdx.x) * 8;
    int c = (int)(idx & (Cq - 1));
    long long row = idx >> 10;
    int tp = (int)(row % (Tq + 1));
    int b  = (int)(row / (Tq + 1));
    f16x8 o;
    if (tp == 0) {
#pragma unroll
        for (int j = 0; j < 8; j++) o[j] = (f16)0.0f;
    } else {
        const float* src = x + (((size_t)b * Tq + (tp - 1)) << 10) + c;
        float4 v0 = *(const float4*)(src);
        float4 v1 = *(const float4*)(src + 4);
        o[0]=(f16)v0.x; o[1]=(f16)v0.y; o[2]=(f16)v0.z; o[3]=(f16)v0.w;
        o[4]=(f16)v1.x; o[5]=(f16)v1.y; o[6]=(f16)v1.z; o[7]=(f16)v1.w;
    }
    *(f16x8*)(Xs + idx) = o;
}

// ---------------- prep: W^T f16 [N=3072][K=2048] ----------------
__global__ void prep_wt(const float* __restrict__ w, f16* __restrict__ WT) {
    __shared__ float t[32][33];
    int kb = blockIdx.x * 32, nb = blockIdx.y * 32;
    int tx = threadIdx.x & 31, ty = threadIdx.x >> 5;
#pragma unroll
    for (int j = 0; j < 32; j += 8)
        t[ty + j][tx] = w[(size_t)(kb + ty + j) * Nq + nb + tx];
    __syncthreads();
#pragma unroll
    for (int j = 0; j < 32; j += 8)
        WT[(size_t)(nb + ty + j) * Kq + kb + tx] = (f16)t[tx][ty + j];
}

// ---------------- 256x256 role-split GEMM + gate epilogue ----------------
// 8 waves (2M x 4N). LDS [A0|B0|A1|B1] 32KB each, dbuf 128KiB,
// swizzle lds(row,cb)=global(row, cb^((row&7)<<4)).
// Per K-tile (buf c): VMC(0)+BAR at boundary (stages issued a full tile ago ->
// drain free; BAR orders all waves' reads-of-c-done before next stage-writes).
// Group wm=0: {A0,B0}r MM(0,0) | {B1}r MM(0,1) | {A1}r MM(1,0) MM(1,1)
// Group wm=1: {A1,B1}r MM(1,1) | {B0}r MM(1,0) | {A0}r MM(0,0) MM(0,1)
// lgkm counts identical (12/8/0); stages for c^1 issued after the 12-read group.
__global__ __launch_bounds__(512, 2) void gemm_gates8(
    const f16* __restrict__ Xs, const f16* __restrict__ WT,
    const float* __restrict__ bias,
    f16* __restrict__ H, f16* __restrict__ F, f16* __restrict__ O)
{
    __shared__ __align__(16) f16 smem[65536];   // 128 KiB
    const int tid  = threadIdx.x;
    const int lane = tid & 63;
    const int wave = tid >> 6;
    const int wm = wave >> 2;            // 0..1  (also the role-split group)
    const int wn = wave & 3;             // 0..3

    // T1: XCD swizzle, nwg=768 (768%8==0), chunk=96, N-minor for A-panel L2 reuse
    const int wg  = blockIdx.x;
    const int swz = (wg & 7) * 96 + (wg >> 3);
    const int mT  = swz / 12, nT = swz - mT * 12;
    const int rM  = mT * 256;
    const int nB  = nT * 256;
    const int b   = rM >> 11;
    const int t0  = rM & (Tq - 1);
    const size_t xsRow0 = (size_t)b * (Tq + 1) + t0;

    const int srow = tid >> 3;
    const int scol = (((tid & 7) ^ (srow & 7))) * 8;   // pre-swizzled source col (f16)
    const f16* Abase = Xs + (xsRow0 + srow) * (size_t)Cq + scol;   // lda = Cq (overlapping windows)
    const f16* Bbase = WT + (size_t)(nB + srow) * Kq + scol;
    const int dstT = tid * 16;

#define STAGE_A(c, h, kt) do { \
    const f16* _s = Abase + (size_t)((h) * 128) * Cq + (kt) * 64; \
    int _d = (c) * 65536 + (h) * 16384 + dstT; \
    __builtin_amdgcn_global_load_lds((const AS1 void*)_s, \
        (AS3 void*)((char*)smem + _d), 16, 0, 0); \
    __builtin_amdgcn_global_load_lds((const AS1 void*)(_s + (size_t)64 * Cq), \
        (AS3 void*)((char*)smem + _d + 8192), 16, 0, 0); \
} while (0)

#define STAGE_B(c, h, kt) do { \
    const f16* _s = Bbase + (size_t)((h) * 128) * Kq + (kt) * 64; \
    int _d = 32768 + (c) * 65536 + (h) * 16384 + dstT; \
    __builtin_amdgcn_global_load_lds((const AS1 void*)_s, \
        (AS3 void*)((char*)smem + _d), 16, 0, 0); \
    __builtin_amdgcn_global_load_lds((const AS1 void*)(_s + (size_t)64 * Kq), \
        (AS3 void*)((char*)smem + _d + 8192), 16, 0, 0); \
} while (0)

    // ds_read per-lane constants (16x16x32 fragment layout)
    const int rAoff = (wm * 64 + (lane & 15)) * 128;
    const int rBoff = (wn * 32 + (lane & 15)) * 128;
    const int ksw0 = (((lane >> 4) * 16)) ^ ((lane & 7) << 4);
    const int ksw1 = (64 + ((lane >> 4) * 16)) ^ ((lane & 7) << 4);

    f32x4 acc[2][2][4][2] = {};   // [h][g][mi][ni]
    f16x8 afA[4][2], afB[4][2], bg0[2][2], bg1[2][2];

#define LOADA_TO(c, h, dst) do { \
    const char* _a = (const char*)smem + (c) * 65536 + (h) * 16384 + rAoff; \
    _Pragma("unroll") \
    for (int mi = 0; mi < 4; mi++) { \
        dst[mi][0] = *(const f16x8*)(_a + mi * 2048 + ksw0); \
        dst[mi][1] = *(const f16x8*)(_a + mi * 2048 + ksw1); \
    } \
} while (0)

#define LOADB_TO(c, g, breg) do { \
    const char* _b = (const char*)smem + 32768 + (c) * 65536 + (g) * 16384 + rBoff; \
    _Pragma("unroll") \
    for (int ni = 0; ni < 2; ni++) { \
        breg[ni][0] = *(const f16x8*)(_b + ni * 2048 + ksw0); \
        breg[ni][1] = *(const f16x8*)(_b + ni * 2048 + ksw1); \
    } \
} while (0)

// ks-outer: 8 independent MFMAs between accumulator reuses
#define MM(h, g, afr, breg) do { \
    _Pragma("unroll") \
    for (int ks = 0; ks < 2; ks++) \
    _Pragma("unroll") \
    for (int mi = 0; mi < 4; mi++) \
    _Pragma("unroll") \
    for (int ni = 0; ni < 2; ni++) \
        acc[h][g][mi][ni] = __builtin_amdgcn_mfma_f32_16x16x32_f16(afr[mi][ks], breg[ni][ks], acc[h][g][mi][ni], 0, 0, 0); \
} while (0)

#define BAR()  __builtin_amdgcn_s_barrier()
#define SB0()  __builtin_amdgcn_sched_barrier(0)
#define PRIO1  __builtin_amdgcn_s_setprio(1)
#define PRIO0  __builtin_amdgcn_s_setprio(0)
#define LGKMC(n) asm volatile("s_waitcnt lgkmcnt(" #n ")" ::: "memory")
#define VMC(n)   asm volatile("s_waitcnt vmcnt(" #n ")" ::: "memory")

// Role-split tile body. lgkm counts are positional over the SB0-pinned read
// groups: 12 issued, then 4, then 8 -> waits 12 / 8 / 0.
#define KTILE_G0(c, ktn) do { \
    LOADA_TO(c, 0, afA); LOADB_TO(c, 0, bg0); \
    SB0(); \
    STAGE_A(1 - (c), 0, ktn); STAGE_B(1 - (c), 0, ktn); \
    STAGE_B(1 - (c), 1, ktn); STAGE_A(1 - (c), 1, ktn); \
    SB0(); LGKMC(0); SB0(); \
    PRIO1; MM(0, 0, afA, bg0); PRIO0; \
    LOADB_TO(c, 1, bg1); \
    SB0(); LGKMC(0); SB0(); \
    PRIO1; MM(0, 1, afA, bg1); PRIO0; \
    LOADA_TO(c, 1, afB); \
    SB0(); LGKMC(0); SB0(); \
    PRIO1; MM(1, 0, afB, bg0); MM(1, 1, afB, bg1); PRIO0; \
} while (0)

#define KTILE_G1(c, ktn) do { \
    LOADA_TO(c, 1, afB); LOADB_TO(c, 1, bg1); \
    SB0(); \
    STAGE_A(1 - (c), 0, ktn); STAGE_B(1 - (c), 0, ktn); \
    STAGE_B(1 - (c), 1, ktn); STAGE_A(1 - (c), 1, ktn); \
    SB0(); LGKMC(0); SB0(); \
    PRIO1; MM(1, 1, afB, bg1); PRIO0; \
    LOADB_TO(c, 0, bg0); \
    SB0(); LGKMC(0); SB0(); \
    PRIO1; MM(1, 0, afB, bg0); PRIO0; \
    LOADA_TO(c, 0, afA); \
    SB0(); LGKMC(0); SB0(); \
    PRIO1; MM(0, 0, afA, bg0); MM(0, 1, afA, bg1); PRIO0; \
} while (0)

#define KTILE(c, ktn) do { \
    VMC(0); BAR(); \
    if (wm == 0) { KTILE_G0(c, ktn); } else { KTILE_G1(c, ktn); } \
} while (0)

    // prologue: issue K-tile 0's 4 halves into buf0. First KTILE's VMC(0)+BAR drains.
    STAGE_A(0, 0, 0); STAGE_B(0, 0, 0); STAGE_B(0, 1, 0); STAGE_A(0, 1, 0);

    for (int t = 0; t < 32; t += 2) {
        KTILE(0, t + 1);
        KTILE(1, t + 2);   // t+2==32 on last iter: garbage stage, in-bounds, never consumed
    }

    // epilogue: C/D layout col=lane&15, row=(lane>>4)*4+j
    const int gate = nB >> 10;
    f16* G = (gate == 0) ? H : ((gate == 1) ? F : O);
#pragma unroll
    for (int h = 0; h < 2; h++)
#pragma unroll
    for (int g = 0; g < 2; g++)
#pragma unroll
    for (int ni = 0; ni < 2; ni++) {
        const int col = nB + g * 128 + wn * 32 + ni * 16 + (lane & 15);
        const int u = col & (Uq - 1);
        const float bv = bias[col];
#pragma unroll
        for (int mi = 0; mi < 4; mi++)
#pragma unroll
        for (int j = 0; j < 4; j++) {
            const int row = rM + h * 128 + wm * 64 + mi * 16 + ((lane >> 4) << 2) + j;
            float v = acc[h][g][mi][ni][j] + bv;
            float r;
            if (gate == 0) r = 1.0f - 2.0f / (__expf(2.0f * v) + 1.0f);  // tanh
            else           r = 1.0f / (1.0f + __expf(-v));                // sigmoid
            G[(size_t)row * Uq + u] = (f16)r;
        }
    }
}

// ---------------- fo-pool scan (chunked, 2 passes) ----------------
__global__ void scan_pass1(const f16* __restrict__ F, const f16* __restrict__ H,
                           float* __restrict__ Ach, float* __restrict__ Bch) {
    int idx = blockIdx.x * blockDim.x + threadIdx.x;
    int u  = idx & (Uq - 1);
    int ch = (idx >> 10) & (NCH - 1);
    int b  = idx >> 15;
    size_t base = ((size_t)b * Tq + ch * CHL) * Uq + u;
    float a = 1.0f, c = 0.0f;
    for (int i = 0; i < CHL; i++) {
        float f = (float)F[base + (size_t)i * Uq];
        float h = (float)H[base + (size_t)i * Uq];
        c = f * c + (1.0f - f) * h;
        a *= f;
    }
    Ach[idx] = a;
    Bch[idx] = c;
}

// pass3 with inlined carry scan: carry over ch' < ch from L2-resident Ach/Bch.
__global__ void scan_pass3(const f16* __restrict__ F, const f16* __restrict__ H,
                           const f16* __restrict__ O,
                           const float* __restrict__ Ach, const float* __restrict__ Bch,
                           float* __restrict__ out) {
    int idx = blockIdx.x * blockDim.x + threadIdx.x;
    int u  = idx & (Uq - 1);
    int ch = (idx >> 10) & (NCH - 1);
    int b  = idx >> 15;
    int cbase = (b * NCH) * Uq + u;
    float c = 0.0f;
    for (int ch2 = 0; ch2 < ch; ch2++) {
        int o = cbase + ch2 * Uq;
        c = Ach[o] * c + Bch[o];
    }
    size_t base = ((size_t)b * Tq + ch * CHL) * Uq + u;
    for (int i = 0; i < CHL; i++) {
        float f = (float)F[base + (size_t)i * Uq];
        float h = (float)H[base + (size_t)i * Uq];
        c = f * c + (1.0f - f) * h;
        out[base + (size_t)i * Uq] = (float)O[base + (size_t)i * Uq] * c;
    }
}

// ---------------- launch ----------------
extern "C" void kernel_launch(void* const* d_in, const int* in_sizes, int n_in,
                              void* d_out, int out_size, void* d_ws, size_t ws_size,
                              hipStream_t stream) {
    const float* x    = (const float*)d_in[0];
    const float* w    = (const float*)d_in[1];
    const float* bias = (const float*)d_in[2];
    float* out = (float*)d_out;
    char* ws = (char*)d_ws;

    f16* Xs   = (f16*)(ws);                       // 8*2049*1024*2 = 33,570,816
    f16* WT   = (f16*)(ws + 33570816);            // 12,582,912
    f16* Hh   = (f16*)(ws + 46153728);            // 33,554,432
    f16* Fh   = (f16*)(ws + 79708160);            // 33,554,432
    f16* Oh   = (f16*)(ws + 113262592);           // 33,554,432
    float* Ach = (float*)(ws + 146817024);        // 1,048,576
    float* Bch = (float*)(ws + 147865600);        // 1,048,576

    prep_xs<<<(Bq * (Tq + 1) * Cq) / (8 * 256), 256, 0, stream>>>(x, Xs);
    prep_wt<<<dim3(Kq / 32, Nq / 32), 256, 0, stream>>>(w, WT);
    gemm_gates8<<<(Mq / 256) * (Nq / 256), 512, 0, stream>>>(Xs, WT, bias, Hh, Fh, Oh);
    scan_pass1<<<(Bq * NCH * Uq) / 256, 256, 0, stream>>>(Fh, Hh, Ach, Bch);
    scan_pass3<<<(Bq * NCH * Uq) / 256, 256, 0, stream>>>(Fh, Hh, Oh, Ach, Bch, out);
}

// Round 12
// 258.013 us; speedup vs baseline: 2.9509x; 2.9509x over previous
//
#include <hip/hip_runtime.h>

// QRNN fused: causal conv1d(window=2) as f16 MFMA GEMM + gates + fo-pool scan.
// Shapes: B=8, T=2048, C=1024, U=1024 -> GEMM M=16384, K=2048, N=3072.
// R12: role-split WITHOUT divergence (R11's if/else doubled live ranges ->
//      spill, 1.5GB scratch traffic). All waves run R9's identical static
//      code; quadrant traversal order differs per group via f=wm XOR folded
//      into LDS addresses + epilogue coords. acc slot s = logical quadrant s^f.

typedef _Float16 f16;
typedef _Float16 f16x8 __attribute__((ext_vector_type(8)));
typedef float    f32x4 __attribute__((ext_vector_type(4)));

#define Bq 8
#define Tq 2048
#define Cq 1024
#define Uq 1024
#define Mq (Bq*Tq)    // 16384
#define Kq (2*Cq)     // 2048
#define Nq (3*Uq)     // 3072
#define NCH 32
#define CHL (Tq/NCH)

#define AS1 __attribute__((address_space(1)))
#define AS3 __attribute__((address_space(3)))

// ---------------- prep: Xs[b][1+t][c] = x[b][t][c] (f16), Xs[b][0][:] = 0 ----------------
__global__ void prep_xs(const float* __restrict__ x, f16* __restrict__ Xs) {
    long long idx = ((long long)blockIdx.x * blockDim.x + threadIdx.x) * 8;
    int c = (int)(idx & (Cq - 1));
    long long row = idx >> 10;
    int tp = (int)(row % (Tq + 1));
    int b  = (int)(row / (Tq + 1));
    f16x8 o;
    if (tp == 0) {
#pragma unroll
        for (int j = 0; j < 8; j++) o[j] = (f16)0.0f;
    } else {
        const float* src = x + (((size_t)b * Tq + (tp - 1)) << 10) + c;
        float4 v0 = *(const float4*)(src);
        float4 v1 = *(const float4*)(src + 4);
        o[0]=(f16)v0.x; o[1]=(f16)v0.y; o[2]=(f16)v0.z; o[3]=(f16)v0.w;
        o[4]=(f16)v1.x; o[5]=(f16)v1.y; o[6]=(f16)v1.z; o[7]=(f16)v1.w;
    }
    *(f16x8*)(Xs + idx) = o;
}

// ---------------- prep: W^T f16 [N=3072][K=2048] ----------------
__global__ void prep_wt(const float* __restrict__ w, f16* __restrict__ WT) {
    __shared__ float t[32][33];
    int kb = blockIdx.x * 32, nb = blockIdx.y * 32;
    int tx = threadIdx.x & 31, ty = threadIdx.x >> 5;
#pragma unroll
    for (int j = 0; j < 32; j += 8)
        t[ty + j][tx] = w[(size_t)(kb + ty + j) * Nq + nb + tx];
    __syncthreads();
#pragma unroll
    for (int j = 0; j < 32; j += 8)
        WT[(size_t)(nb + ty + j) * Kq + kb + tx] = (f16)t[tx][ty + j];
}

// ---------------- 256x256 role-split GEMM + gate epilogue ----------------
// 8 waves (2M x 4N). LDS [A0|B0|A1|B1] 32KB each, dbuf 128KiB,
// swizzle lds(row,cb)=global(row, cb^((row&7)<<4)).
// Per K-tile (buf c): VMC(0)+BAR at boundary; issue 24 ds_reads in
// group-logical order (first-needed quadrants first), 8 stages; counted
// lgkm 12/8/0 between MFMA clusters. Group f=0: A0,B0|B1|A1;
// group f=1: A1,B1|B0|A0 (via address XOR). Same static code both groups.
__global__ __launch_bounds__(512, 2) void gemm_gates8(
    const f16* __restrict__ Xs, const f16* __restrict__ WT,
    const float* __restrict__ bias,
    f16* __restrict__ H, f16* __restrict__ F, f16* __restrict__ O)
{
    __shared__ __align__(16) f16 smem[65536];   // 128 KiB
    const int tid  = threadIdx.x;
    const int lane = tid & 63;
    const int wave = tid >> 6;
    const int wm = wave >> 2;            // 0..1  (role-split group f)
    const int wn = wave & 3;             // 0..3
    const int fofs = wm << 14;           // quadrant-order XOR (LDS byte offset)

    // T1: XCD swizzle, nwg=768 (768%8==0), chunk=96, N-minor for A-panel L2 reuse
    const int wg  = blockIdx.x;
    const int swz = (wg & 7) * 96 + (wg >> 3);
    const int mT  = swz / 12, nT = swz - mT * 12;
    const int rM  = mT * 256;
    const int nB  = nT * 256;
    const int b   = rM >> 11;
    const int t0  = rM & (Tq - 1);
    const size_t xsRow0 = (size_t)b * (Tq + 1) + t0;

    const int srow = tid >> 3;
    const int scol = (((tid & 7) ^ (srow & 7))) * 8;   // pre-swizzled source col (f16)
    const f16* Abase = Xs + (xsRow0 + srow) * (size_t)Cq + scol;   // lda = Cq (overlapping windows)
    const f16* Bbase = WT + (size_t)(nB + srow) * Kq + scol;
    const int dstT = tid * 16;

#define STAGE_A(c, h, kt) do { \
    const f16* _s = Abase + (size_t)((h) * 128) * Cq + (kt) * 64; \
    int _d = (c) * 65536 + (h) * 16384 + dstT; \
    __builtin_amdgcn_global_load_lds((const AS1 void*)_s, \
        (AS3 void*)((char*)smem + _d), 16, 0, 0); \
    __builtin_amdgcn_global_load_lds((const AS1 void*)(_s + (size_t)64 * Cq), \
        (AS3 void*)((char*)smem + _d + 8192), 16, 0, 0); \
} while (0)

#define STAGE_B(c, h, kt) do { \
    const f16* _s = Bbase + (size_t)((h) * 128) * Kq + (kt) * 64; \
    int _d = 32768 + (c) * 65536 + (h) * 16384 + dstT; \
    __builtin_amdgcn_global_load_lds((const AS1 void*)_s, \
        (AS3 void*)((char*)smem + _d), 16, 0, 0); \
    __builtin_amdgcn_global_load_lds((const AS1 void*)(_s + (size_t)64 * Kq), \
        (AS3 void*)((char*)smem + _d + 8192), 16, 0, 0); \
} while (0)

    // ds_read per-lane constants (16x16x32 fragment layout)
    const int rAoff = (wm * 64 + (lane & 15)) * 128;
    const int rBoff = (wn * 32 + (lane & 15)) * 128;
    const int ksw0 = (((lane >> 4) * 16)) ^ ((lane & 7) << 4);
    const int ksw1 = (64 + ((lane >> 4) * 16)) ^ ((lane & 7) << 4);

    f32x4 acc[2][2][4][2] = {};   // [sA][sB][mi][ni]; slot s = logical quadrant s^f
    f16x8 afA[4][2], afB[4][2], bg0[2][2], bg1[2][2];

// slot-addressed loads: slot s reads LDS half (s XOR f) via fofs
#define LOADA_TO(c, s, dst) do { \
    const char* _a = (const char*)smem + (c) * 65536 + (((s) << 14) ^ fofs) + rAoff; \
    _Pragma("unroll") \
    for (int mi = 0; mi < 4; mi++) { \
        dst[mi][0] = *(const f16x8*)(_a + mi * 2048 + ksw0); \
        dst[mi][1] = *(const f16x8*)(_a + mi * 2048 + ksw1); \
    } \
} while (0)

#define LOADB_TO(c, s, breg) do { \
    const char* _b = (const char*)smem + 32768 + (c) * 65536 + (((s) << 14) ^ fofs) + rBoff; \
    _Pragma("unroll") \
    for (int ni = 0; ni < 2; ni++) { \
        breg[ni][0] = *(const f16x8*)(_b + ni * 2048 + ksw0); \
        breg[ni][1] = *(const f16x8*)(_b + ni * 2048 + ksw1); \
    } \
} while (0)

// ks-outer: 8 independent MFMAs between accumulator reuses
#define MM(s, t, afr, breg) do { \
    _Pragma("unroll") \
    for (int ks = 0; ks < 2; ks++) \
    _Pragma("unroll") \
    for (int mi = 0; mi < 4; mi++) \
    _Pragma("unroll") \
    for (int ni = 0; ni < 2; ni++) \
        acc[s][t][mi][ni] = __builtin_amdgcn_mfma_f32_16x16x32_f16(afr[mi][ks], breg[ni][ks], acc[s][t][mi][ni], 0, 0, 0); \
} while (0)

#define BAR()  __builtin_amdgcn_s_barrier()
#define SB0()  __builtin_amdgcn_sched_barrier(0)
#define PRIO1  __builtin_amdgcn_s_setprio(1)
#define PRIO0  __builtin_amdgcn_s_setprio(0)
#define LGKMC(n) asm volatile("s_waitcnt lgkmcnt(" #n ")" ::: "memory")
#define VMC(n)   asm volatile("s_waitcnt vmcnt(" #n ")" ::: "memory")

// Single-barrier K-tile (R9 skeleton). lgkm counts positional over the
// SB0-pinned read groups: 24 issued -> 12 (drains afA,bg0) / 8 (bg1) / 0 (afB).
#define KTILE(c, ktn) do { \
    VMC(0); BAR(); \
    LOADA_TO(c, 0, afA); LOADB_TO(c, 0, bg0); \
    SB0(); \
    LOADB_TO(c, 1, bg1); \
    SB0(); \
    LOADA_TO(c, 1, afB); \
    SB0(); \
    STAGE_A(1 - (c), 0, ktn); STAGE_B(1 - (c), 0, ktn); \
    STAGE_B(1 - (c), 1, ktn); STAGE_A(1 - (c), 1, ktn); \
    SB0(); LGKMC(12); SB0(); \
    PRIO1; MM(0, 0, afA, bg0); PRIO0; \
    SB0(); LGKMC(8); SB0(); \
    PRIO1; MM(0, 1, afA, bg1); PRIO0; \
    SB0(); LGKMC(0); SB0(); \
    PRIO1; MM(1, 0, afB, bg0); MM(1, 1, afB, bg1); PRIO0; \
} while (0)

    // prologue: issue K-tile 0's 4 halves into buf0. First KTILE's VMC(0)+BAR drains.
    STAGE_A(0, 0, 0); STAGE_B(0, 0, 0); STAGE_B(0, 1, 0); STAGE_A(0, 1, 0);

    for (int t = 0; t < 32; t += 2) {
        KTILE(0, t + 1);
        KTILE(1, t + 2);   // t+2==32 on last iter: garbage stage, in-bounds, never consumed
    }

    // epilogue: slot (s,t) = logical quadrant (s^f, t^f).
    // C/D layout col=lane&15, row=(lane>>4)*4+j
    const int gate = nB >> 10;
    f16* G = (gate == 0) ? H : ((gate == 1) ? F : O);
#pragma unroll
    for (int s = 0; s < 2; s++)
#pragma unroll
    for (int t = 0; t < 2; t++)
#pragma unroll
    for (int ni = 0; ni < 2; ni++) {
        const int col = nB + (t ^ wm) * 128 + wn * 32 + ni * 16 + (lane & 15);
        const int u = col & (Uq - 1);
        const float bv = bias[col];
#pragma unroll
        for (int mi = 0; mi < 4; mi++)
#pragma unroll
        for (int j = 0; j < 4; j++) {
            const int row = rM + (s ^ wm) * 128 + wm * 64 + mi * 16 + ((lane >> 4) << 2) + j;
            float v = acc[s][t][mi][ni][j] + bv;
            float r;
            if (gate == 0) r = 1.0f - 2.0f / (__expf(2.0f * v) + 1.0f);  // tanh
            else           r = 1.0f / (1.0f + __expf(-v));                // sigmoid
            G[(size_t)row * Uq + u] = (f16)r;
        }
    }
}

// ---------------- fo-pool scan (chunked, 2 passes) ----------------
__global__ void scan_pass1(const f16* __restrict__ F, const f16* __restrict__ H,
                           float* __restrict__ Ach, float* __restrict__ Bch) {
    int idx = blockIdx.x * blockDim.x + threadIdx.x;
    int u  = idx & (Uq - 1);
    int ch = (idx >> 10) & (NCH - 1);
    int b  = idx >> 15;
    size_t base = ((size_t)b * Tq + ch * CHL) * Uq + u;
    float a = 1.0f, c = 0.0f;
    for (int i = 0; i < CHL; i++) {
        float f = (float)F[base + (size_t)i * Uq];
        float h = (float)H[base + (size_t)i * Uq];
        c = f * c + (1.0f - f) * h;
        a *= f;
    }
    Ach[idx] = a;
    Bch[idx] = c;
}

// pass3 with inlined carry scan: carry over ch' < ch from L2-resident Ach/Bch.
__global__ void scan_pass3(const f16* __restrict__ F, const f16* __restrict__ H,
                           const f16* __restrict__ O,
                           const float* __restrict__ Ach, const float* __restrict__ Bch,
                           float* __restrict__ out) {
    int idx = blockIdx.x * blockDim.x + threadIdx.x;
    int u  = idx & (Uq - 1);
    int ch = (idx >> 10) & (NCH - 1);
    int b  = idx >> 15;
    int cbase = (b * NCH) * Uq + u;
    float c = 0.0f;
    for (int ch2 = 0; ch2 < ch; ch2++) {
        int o = cbase + ch2 * Uq;
        c = Ach[o] * c + Bch[o];
    }
    size_t base = ((size_t)b * Tq + ch * CHL) * Uq + u;
    for (int i = 0; i < CHL; i++) {
        float f = (float)F[base + (size_t)i * Uq];
        float h = (float)H[base + (size_t)i * Uq];
        c = f * c + (1.0f - f) * h;
        out[base + (size_t)i * Uq] = (float)O[base + (size_t)i * Uq] * c;
    }
}

// ---------------- launch ----------------
extern "C" void kernel_launch(void* const* d_in, const int* in_sizes, int n_in,
                              void* d_out, int out_size, void* d_ws, size_t ws_size,
                              hipStream_t stream) {
    const float* x    = (const float*)d_in[0];
    const float* w    = (const float*)d_in[1];
    const float* bias = (const float*)d_in[2];
    float* out = (float*)d_out;
    char* ws = (char*)d_ws;

    f16* Xs   = (f16*)(ws);                       // 8*2049*1024*2 = 33,570,816
    f16* WT   = (f16*)(ws + 33570816);            // 12,582,912
    f16* Hh   = (f16*)(ws + 46153728);            // 33,554,432
    f16* Fh   = (f16*)(ws + 79708160);            // 33,554,432
    f16* Oh   = (f16*)(ws + 113262592);           // 33,554,432
    float* Ach = (float*)(ws + 146817024);        // 1,048,576
    float* Bch = (float*)(ws + 147865600);        // 1,048,576

    prep_xs<<<(Bq * (Tq + 1) * Cq) / (8 * 256), 256, 0, stream>>>(x, Xs);
    prep_wt<<<dim3(Kq / 32, Nq / 32), 256, 0, stream>>>(w, WT);
    gemm_gates8<<<(Mq / 256) * (Nq / 256), 512, 0, stream>>>(Xs, WT, bias, Hh, Fh, Oh);
    scan_pass1<<<(Bq * NCH * Uq) / 256, 256, 0, stream>>>(Fh, Hh, Ach, Bch);
    scan_pass3<<<(Bq * NCH * Uq) / 256, 256, 0, stream>>>(Fh, Hh, Oh, Ach, Bch, out);
}

// Round 13
// 251.189 us; speedup vs baseline: 3.0310x; 1.0272x over previous
//
#include <hip/hip_runtime.h>

// QRNN fused: causal conv1d(window=2) as f16 MFMA GEMM + gates + fo-pool scan.
// Shapes: B=8, T=2048, C=1024, U=1024 -> GEMM M=16384, K=2048, N=3072.
// R13: GEMM = R5's exact best-measured schedule (201.7 us; R5-R12 established a
//      42-48% lockstep plateau, 6 variants; LDS(2816c)+MFMA(2483c) execute as
//      sum, overlap unreproducible here, 2-block de-phase LDS-infeasible).
//      Tail: prep_xs+prep_wt merged into one launch; scan passes vectorized
//      2u/thread (uint/float2) with dual independent scan chains.

typedef _Float16 f16;
typedef _Float16 f16x2 __attribute__((ext_vector_type(2)));
typedef _Float16 f16x8 __attribute__((ext_vector_type(8)));
typedef float    f32x4 __attribute__((ext_vector_type(4)));

#define Bq 8
#define Tq 2048
#define Cq 1024
#define Uq 1024
#define Mq (Bq*Tq)    // 16384
#define Kq (2*Cq)     // 2048
#define Nq (3*Uq)     // 3072
#define NCH 32
#define CHL (Tq/NCH)
#define NXBLK 8196    // prep_xs blocks: 8*2049*1024/(8*256)

#define AS1 __attribute__((address_space(1)))
#define AS3 __attribute__((address_space(3)))

// ---------------- merged prep: Xs shift-copy (f16) + W^T transpose (f16) ----------------
// blocks [0, NXBLK): Xs[b][1+t][c] = x[b][t][c], Xs[b][0][:] = 0
// blocks [NXBLK, NXBLK+6144): WT[n][k] = w[k][n]
__global__ void prep_all(const float* __restrict__ x, const float* __restrict__ w,
                         f16* __restrict__ Xs, f16* __restrict__ WT) {
    __shared__ float t[32][33];
    if (blockIdx.x < NXBLK) {
        long long idx = ((long long)blockIdx.x * blockDim.x + threadIdx.x) * 8;
        int c = (int)(idx & (Cq - 1));
        long long row = idx >> 10;
        int tp = (int)(row % (Tq + 1));
        int b  = (int)(row / (Tq + 1));
        f16x8 o;
        if (tp == 0) {
#pragma unroll
            for (int j = 0; j < 8; j++) o[j] = (f16)0.0f;
        } else {
            const float* src = x + (((size_t)b * Tq + (tp - 1)) << 10) + c;
            float4 v0 = *(const float4*)(src);
            float4 v1 = *(const float4*)(src + 4);
            o[0]=(f16)v0.x; o[1]=(f16)v0.y; o[2]=(f16)v0.z; o[3]=(f16)v0.w;
            o[4]=(f16)v1.x; o[5]=(f16)v1.y; o[6]=(f16)v1.z; o[7]=(f16)v1.w;
        }
        *(f16x8*)(Xs + idx) = o;
    } else {
        int wtid = blockIdx.x - NXBLK;           // 0..6143
        int kb = (wtid & 63) * 32;               // 64 k-tiles
        int nb = (wtid >> 6) * 32;               // 96 n-tiles
        int tx = threadIdx.x & 31, ty = threadIdx.x >> 5;
#pragma unroll
        for (int j = 0; j < 32; j += 8)
            t[ty + j][tx] = w[(size_t)(kb + ty + j) * Nq + nb + tx];
        __syncthreads();
#pragma unroll
        for (int j = 0; j < 32; j += 8)
            WT[(size_t)(nb + ty + j) * Kq + kb + tx] = (f16)t[tx][ty + j];
    }
}

// ---------------- 256x256 pipelined 4-phase GEMM + gate epilogue (R5 schedule) ----------------
// 8 waves (2M x 4N): wave (wm,wn) owns rows {h*128+wm*64}(64 each), cols
// {g*128+wn*32}(32 each). Phase (h,g) = 16 MFMA 16x16x32.
// LDS [A0|B0|A1|B1] 32KB each, dbuf 128KiB, swizzle lds(row,cb)=global(row,cb^((row&7)<<4)).
// Reads lead one phase (counted lgkm); stages at P1..P4; VM2 at P1/P3/P4 ends.
__global__ __launch_bounds__(512, 2) void gemm_gates8(
    const f16* __restrict__ Xs, const f16* __restrict__ WT,
    const float* __restrict__ bias,
    f16* __restrict__ H, f16* __restrict__ F, f16* __restrict__ O)
{
    __shared__ __align__(16) f16 smem[65536];   // 128 KiB
    const int tid  = threadIdx.x;
    const int lane = tid & 63;
    const int wave = tid >> 6;
    const int wm = wave >> 2;            // 0..1
    const int wn = wave & 3;             // 0..3

    // T1: XCD swizzle, nwg=768 (768%8==0), chunk=96, N-minor for A-panel L2 reuse
    const int wg  = blockIdx.x;
    const int swz = (wg & 7) * 96 + (wg >> 3);
    const int mT  = swz / 12, nT = swz - mT * 12;
    const int rM  = mT * 256;
    const int nB  = nT * 256;
    const int b   = rM >> 11;
    const int t0  = rM & (Tq - 1);
    const size_t xsRow0 = (size_t)b * (Tq + 1) + t0;

    const int srow = tid >> 3;
    const int scol = (((tid & 7) ^ (srow & 7))) * 8;   // pre-swizzled source col (f16)
    const f16* Abase = Xs + (xsRow0 + srow) * (size_t)Cq + scol;   // lda = Cq (overlapping windows)
    const f16* Bbase = WT + (size_t)(nB + srow) * Kq + scol;
    const int dstT = tid * 16;

#define STAGE_A(c, h, kt) do { \
    const f16* _s = Abase + (size_t)((h) * 128) * Cq + (kt) * 64; \
    int _d = (c) * 65536 + (h) * 16384 + dstT; \
    __builtin_amdgcn_global_load_lds((const AS1 void*)_s, \
        (AS3 void*)((char*)smem + _d), 16, 0, 0); \
    __builtin_amdgcn_global_load_lds((const AS1 void*)(_s + (size_t)64 * Cq), \
        (AS3 void*)((char*)smem + _d + 8192), 16, 0, 0); \
} while (0)

#define STAGE_B(c, h, kt) do { \
    const f16* _s = Bbase + (size_t)((h) * 128) * Kq + (kt) * 64; \
    int _d = 32768 + (c) * 65536 + (h) * 16384 + dstT; \
    __builtin_amdgcn_global_load_lds((const AS1 void*)_s, \
        (AS3 void*)((char*)smem + _d), 16, 0, 0); \
    __builtin_amdgcn_global_load_lds((const AS1 void*)(_s + (size_t)64 * Kq), \
        (AS3 void*)((char*)smem + _d + 8192), 16, 0, 0); \
} while (0)

    // ds_read per-lane constants (16x16x32 fragment layout)
    const int rAoff = (wm * 64 + (lane & 15)) * 128;
    const int rBoff = (wn * 32 + (lane & 15)) * 128;
    const int ksw0 = (((lane >> 4) * 16)) ^ ((lane & 7) << 4);
    const int ksw1 = (64 + ((lane >> 4) * 16)) ^ ((lane & 7) << 4);

    f32x4 acc[2][2][4][2] = {};   // [h][g][mi][ni]
    f16x8 afA[4][2], afB[4][2], bg0[2][2], bg1[2][2];

#define LOADA_TO(c, h, dst) do { \
    const char* _a = (const char*)smem + (c) * 65536 + (h) * 16384 + rAoff; \
    _Pragma("unroll") \
    for (int mi = 0; mi < 4; mi++) { \
        dst[mi][0] = *(const f16x8*)(_a + mi * 2048 + ksw0); \
        dst[mi][1] = *(const f16x8*)(_a + mi * 2048 + ksw1); \
    } \
} while (0)

#define LOADB_TO(c, g, breg) do { \
    const char* _b = (const char*)smem + 32768 + (c) * 65536 + (g) * 16384 + rBoff; \
    _Pragma("unroll") \
    for (int ni = 0; ni < 2; ni++) { \
        breg[ni][0] = *(const f16x8*)(_b + ni * 2048 + ksw0); \
        breg[ni][1] = *(const f16x8*)(_b + ni * 2048 + ksw1); \
    } \
} while (0)

#define MM(h, g, afr, breg) do { \
    _Pragma("unroll") \
    for (int mi = 0; mi < 4; mi++) \
    _Pragma("unroll") \
    for (int ni = 0; ni < 2; ni++) { \
        acc[h][g][mi][ni] = __builtin_amdgcn_mfma_f32_16x16x32_f16(afr[mi][0], breg[ni][0], acc[h][g][mi][ni], 0, 0, 0); \
        acc[h][g][mi][ni] = __builtin_amdgcn_mfma_f32_16x16x32_f16(afr[mi][1], breg[ni][1], acc[h][g][mi][ni], 0, 0, 0); \
    } \
} while (0)

#define BAR()  __builtin_amdgcn_s_barrier()
#define SB0()  __builtin_amdgcn_sched_barrier(0)
#define PRIO1  __builtin_amdgcn_s_setprio(1)
#define PRIO0  __builtin_amdgcn_s_setprio(0)
#define LGKMC(n) asm volatile("s_waitcnt lgkmcnt(" #n ")" ::: "memory")
#define VM2()    asm volatile("s_waitcnt vmcnt(2)" ::: "memory")

// R5's verbatim K-tile (best measured: 201.7 us GEMM):
//   P1: read B1(c)->bg1   | MM(0,0) afA,bg0 | VM2+BAR
//   P2: read A1(c)->afB   | MM(0,1) afA,bg1 |
//   P3: (no reads)        | MM(1,0) afB,bg0 | VM2+BAR
//   P4: read A0,B0(c^1)->afA,bg0 | MM(1,1) afB,bg1 | VM2+BAR
#define KTILE(c, ktn) do { \
    /*P1*/ LOADB_TO(c, 1, bg1); STAGE_A(1 - (c), 0, ktn); \
           SB0(); LGKMC(4); SB0(); \
           PRIO1; MM(0, 0, afA, bg0); PRIO0; \
           VM2(); BAR(); \
    /*P2*/ LOADA_TO(c, 1, afB); STAGE_B(1 - (c), 0, ktn); \
           SB0(); LGKMC(8); SB0(); \
           PRIO1; MM(0, 1, afA, bg1); PRIO0; \
    /*P3*/ STAGE_B(1 - (c), 1, ktn); \
           SB0(); LGKMC(0); SB0(); \
           PRIO1; MM(1, 0, afB, bg0); PRIO0; \
           VM2(); BAR(); \
    /*P4*/ LOADA_TO(1 - (c), 0, afA); LOADB_TO(1 - (c), 0, bg0); STAGE_A(1 - (c), 1, ktn); \
           SB0(); LGKMC(12); SB0(); \
           PRIO1; MM(1, 1, afB, bg1); PRIO0; \
           VM2(); BAR(); \
} while (0)

    // prologue: stage K-tile 0 (A0,B0,B1,A1); vmcnt(2) leaves A1 in flight
    // (drained by P1's end VM2 before P2 reads it); pre-read afA,bg0.
    STAGE_A(0, 0, 0); STAGE_B(0, 0, 0); STAGE_B(0, 1, 0); STAGE_A(0, 1, 0);
    asm volatile("s_waitcnt vmcnt(2)" ::: "memory");
    BAR();
    LOADA_TO(0, 0, afA); LOADB_TO(0, 0, bg0);

    for (int t = 0; t < 32; t += 2) {
        KTILE(0, t + 1);
        KTILE(1, t + 2);   // t+2==32 on last iter: garbage stage/pre-read, in-bounds, never consumed
    }

    // epilogue: C/D layout col=lane&15, row=(lane>>4)*4+j
    const int gate = nB >> 10;
    f16* G = (gate == 0) ? H : ((gate == 1) ? F : O);
#pragma unroll
    for (int h = 0; h < 2; h++)
#pragma unroll
    for (int g = 0; g < 2; g++)
#pragma unroll
    for (int ni = 0; ni < 2; ni++) {
        const int col = nB + g * 128 + wn * 32 + ni * 16 + (lane & 15);
        const int u = col & (Uq - 1);
        const float bv = bias[col];
#pragma unroll
        for (int mi = 0; mi < 4; mi++)
#pragma unroll
        for (int j = 0; j < 4; j++) {
            const int row = rM + h * 128 + wm * 64 + mi * 16 + ((lane >> 4) << 2) + j;
            float v = acc[h][g][mi][ni][j] + bv;
            float r;
            if (gate == 0) r = 1.0f - 2.0f / (__expf(2.0f * v) + 1.0f);  // tanh
            else           r = 1.0f / (1.0f + __expf(-v));                // sigmoid
            G[(size_t)row * Uq + u] = (f16)r;
        }
    }
}

// ---------------- fo-pool scan (chunked, 2 passes, 2u/thread) ----------------
__global__ void scan_pass1(const f16* __restrict__ F, const f16* __restrict__ H,
                           float* __restrict__ Ach, float* __restrict__ Bch) {
    int idx = blockIdx.x * blockDim.x + threadIdx.x;   // [b][ch][u2], u2 = u/2
    int u  = (idx & 511) * 2;
    int ch = (idx >> 9) & (NCH - 1);
    int b  = idx >> 14;
    size_t base = ((size_t)b * Tq + ch * CHL) * Uq + u;
    float a0 = 1.0f, a1 = 1.0f, c0 = 0.0f, c1 = 0.0f;
    for (int i = 0; i < CHL; i++) {
        f16x2 fv = *(const f16x2*)(F + base + (size_t)i * Uq);
        f16x2 hv = *(const f16x2*)(H + base + (size_t)i * Uq);
        float f0 = (float)fv[0], f1 = (float)fv[1];
        c0 = f0 * c0 + (1.0f - f0) * (float)hv[0];
        c1 = f1 * c1 + (1.0f - f1) * (float)hv[1];
        a0 *= f0; a1 *= f1;
    }
    int o = ((b * NCH + ch) << 10) + u;
    *(float2*)(Ach + o) = make_float2(a0, a1);
    *(float2*)(Bch + o) = make_float2(c0, c1);
}

// pass3 with inlined carry scan (Ach/Bch L2-resident), 2u/thread.
__global__ void scan_pass3(const f16* __restrict__ F, const f16* __restrict__ H,
                           const f16* __restrict__ O,
                           const float* __restrict__ Ach, const float* __restrict__ Bch,
                           float* __restrict__ out) {
    int idx = blockIdx.x * blockDim.x + threadIdx.x;   // [b][ch][u2]
    int u  = (idx & 511) * 2;
    int ch = (idx >> 9) & (NCH - 1);
    int b  = idx >> 14;
    int cbase = (b * NCH << 10) + u;
    float c0 = 0.0f, c1 = 0.0f;
    for (int ch2 = 0; ch2 < ch; ch2++) {
        int o = cbase + (ch2 << 10);
        float2 av = *(const float2*)(Ach + o);
        float2 bv = *(const float2*)(Bch + o);
        c0 = av.x * c0 + bv.x;
        c1 = av.y * c1 + bv.y;
    }
    size_t base = ((size_t)b * Tq + ch * CHL) * Uq + u;
    for (int i = 0; i < CHL; i++) {
        f16x2 fv = *(const f16x2*)(F + base + (size_t)i * Uq);
        f16x2 hv = *(const f16x2*)(H + base + (size_t)i * Uq);
        f16x2 ov = *(const f16x2*)(O + base + (size_t)i * Uq);
        float f0 = (float)fv[0], f1 = (float)fv[1];
        c0 = f0 * c0 + (1.0f - f0) * (float)hv[0];
        c1 = f1 * c1 + (1.0f - f1) * (float)hv[1];
        *(float2*)(out + base + (size_t)i * Uq) =
            make_float2((float)ov[0] * c0, (float)ov[1] * c1);
    }
}

// ---------------- launch ----------------
extern "C" void kernel_launch(void* const* d_in, const int* in_sizes, int n_in,
                              void* d_out, int out_size, void* d_ws, size_t ws_size,
                              hipStream_t stream) {
    const float* x    = (const float*)d_in[0];
    const float* w    = (const float*)d_in[1];
    const float* bias = (const float*)d_in[2];
    float* out = (float*)d_out;
    char* ws = (char*)d_ws;

    f16* Xs   = (f16*)(ws);                       // 8*2049*1024*2 = 33,570,816
    f16* WT   = (f16*)(ws + 33570816);            // 12,582,912
    f16* Hh   = (f16*)(ws + 46153728);            // 33,554,432
    f16* Fh   = (f16*)(ws + 79708160);            // 33,554,432
    f16* Oh   = (f16*)(ws + 113262592);           // 33,554,432
    float* Ach = (float*)(ws + 146817024);        // 1,048,576
    float* Bch = (float*)(ws + 147865600);        // 1,048,576

    prep_all<<<NXBLK + 6144, 256, 0, stream>>>(x, w, Xs, WT);
    gemm_gates8<<<(Mq / 256) * (Nq / 256), 512, 0, stream>>>(Xs, WT, bias, Hh, Fh, Oh);
    scan_pass1<<<(Bq * NCH * (Uq / 2)) / 256, 256, 0, stream>>>(Fh, Hh, Ach, Bch);
    scan_pass3<<<(Bq * NCH * (Uq / 2)) / 256, 256, 0, stream>>>(Fh, Hh, Oh, Ach, Bch, out);
}